// Round 3
// baseline (1087.850 us; speedup 1.0000x reference)
//
#include <hip/hip_runtime.h>
#include <hip/hip_bf16.h>

// Attention4DDownsample — fused, one workgroup per batch element.
// R7: 512 thr, 72,224 B LDS => 2 blocks/CU; amdgpu_waves_per_eu(4) => VGPR cap 128
// (R5/R6 were silently capped at 64 VGPR -> 190-230 MB scratch traffic, the real
// bottleneck per WRITE_SIZE). Zero scratch by construction: all per-thread arrays
// compile-time indexed. v-path: 4 passes x 128 ch, nt-major vGEMM (z amortized),
// fused v_local+PV per wave (lane map == MFMA C layout), results in regs until
// xs dies, then rout overlays xs. 12 barriers.

#define DIMC 384
#define NPOS 49
#define NHKD 128
#define DHC  512
#define OUTC 384

// ws bf16 weight offsets (elements)
#define OFF_KW  0
#define OFF_VW  49152
#define OFF_QPW 245760
#define OFF_PW  294912
#define W_TOT   491520
// BN fold table (float2, after W_TOT bf16 elems): k,q,v,vl,p
#define BN_K  0
#define BN_Q  128
#define BN_V  256
#define BN_VL 768
#define BN_P  1280
#define BN_TOT 1664

// LDS (bf16 element offsets), total 36,112 elems = 72,224 B (2 blocks/CU)
#define XS_OFF   0        // xs [49][392]; rout [16][520] overlays after last vGEMM
#define QIN_OFF  19208    // qin [16][392]; attnS [8][16][64] (swz) overlays after PD
#define KT_OFF   27400    // kt [49][136] (stale reads to row 63 stay in-bounds)
#define QSM_OFF  34064    // qsm [8][16][16]
#define VSM_OFF  27400    // vsm [128][64] (swz), overlays kt+qsm after bar4
#define SMEM_ELEMS 36112

typedef __attribute__((ext_vector_type(8))) __bf16 bf16x8;
typedef __attribute__((ext_vector_type(4))) float f32x4;

static __device__ __forceinline__ __hip_bfloat16 f2b(float x) { return __float2bfloat16(x); }
static __device__ __forceinline__ float b2f(__hip_bfloat16 x) { return __bfloat162float(x); }
static __device__ __forceinline__ bf16x8 ld8(const __hip_bfloat16* p) { return *(const bf16x8*)p; }
static __device__ __forceinline__ f32x4 fzero() {
  f32x4 z; z[0] = 0.f; z[1] = 0.f; z[2] = 0.f; z[3] = 0.f; return z;
}
static __device__ __forceinline__ bf16x8 bzero() {
  bf16x8 z;
  #pragma unroll
  for (int j = 0; j < 8; ++j) z[j] = (__bf16)0.0f;
  return z;
}

// ---------------- prep: fp32 weights -> bf16 in ws; BN fold -> float2 table ----------------
__global__ void prep_weights(const float* __restrict__ kw, const float* __restrict__ vw,
                             const float* __restrict__ qpw, const float* __restrict__ pw,
                             const float* __restrict__ kb,  const float* __restrict__ kbn,
                             const float* __restrict__ qpb, const float* __restrict__ qbn,
                             const float* __restrict__ vb,  const float* __restrict__ vbn,
                             const float* __restrict__ vlb, const float* __restrict__ vlbn,
                             const float* __restrict__ pb,  const float* __restrict__ pbn,
                             __hip_bfloat16* __restrict__ wsb) {
  const int gid = blockIdx.x * blockDim.x + threadIdx.x;
  const int stride = gridDim.x * blockDim.x;
  for (int i = gid; i < W_TOT; i += stride) {
    float v;
    if (i < OFF_VW)       v = kw[i - OFF_KW];
    else if (i < OFF_QPW) v = vw[i - OFF_VW];
    else if (i < OFF_PW)  v = qpw[i - OFF_QPW];
    else                  v = pw[i - OFF_PW];
    wsb[i] = f2b(v);
  }
  float2* bnt = (float2*)(wsb + W_TOT);
  for (int i = gid; i < BN_TOT; i += stride) {
    const float *bn, *cb; int ch, C;
    if (i < BN_Q)        { bn = kbn;  cb = kb;  ch = i;         C = NHKD; }
    else if (i < BN_V)   { bn = qbn;  cb = qpb; ch = i - BN_Q;  C = NHKD; }
    else if (i < BN_VL)  { bn = vbn;  cb = vb;  ch = i - BN_V;  C = DHC;  }
    else if (i < BN_P)   { bn = vlbn; cb = vlb; ch = i - BN_VL; C = DHC;  }
    else                 { bn = pbn;  cb = pb;  ch = i - BN_P;  C = OUTC; }
    const float g = bn[ch], be = bn[C + ch], mu = bn[2*C + ch], va = bn[3*C + ch];
    const float s = g * rsqrtf(va + 1e-5f);
    bnt[i] = make_float2(s, be + (cb[ch] - mu) * s);
  }
}

// ---------------- main fused kernel ----------------
__global__ __attribute__((amdgpu_flat_work_group_size(512, 512), amdgpu_waves_per_eu(4)))
void attn4d_kernel(
    const float* __restrict__ x,
    const float* __restrict__ qlw, const float* __restrict__ qlb,
    const float* __restrict__ vlw,
    const float* __restrict__ ab,  const int* __restrict__ bidx,
    const __hip_bfloat16* __restrict__ wsb,
    int n_off, float* __restrict__ out)
{
  __shared__ __align__(16) __hip_bfloat16 smem[SMEM_ELEMS];
  __hip_bfloat16* xs    = smem + XS_OFF;     // [49][392]
  __hip_bfloat16* rout  = smem + XS_OFF;     // [16][520], overlays xs (post pass 3 vGEMM)
  __hip_bfloat16* qin   = smem + QIN_OFF;    // [16][392]
  __hip_bfloat16* attnS = smem + QIN_OFF;    // [8][16][64] swz, overlays qin (post PD)
  __hip_bfloat16* kt    = smem + KT_OFF;     // [49][136]
  __hip_bfloat16* qsm   = smem + QSM_OFF;    // [8][16][16]
  __hip_bfloat16* vsm   = smem + VSM_OFF;    // [128][64] swz, overlays kt+qsm (post bar4)

  const __hip_bfloat16* kwb  = wsb + OFF_KW;
  const __hip_bfloat16* vwb  = wsb + OFF_VW;
  const __hip_bfloat16* qpwb = wsb + OFF_QPW;
  const __hip_bfloat16* pwb  = wsb + OFF_PW;
  const float2* bnt = (const float2*)(wsb + W_TOT);

  const int tid  = threadIdx.x;
  const int lane = tid & 63;
  const int wave = tid >> 6;     // 0..7
  const int quad = lane >> 4;    // 0..3
  const int l15  = lane & 15;
  const int b    = blockIdx.x;

  // ---- P0: stage x[b] (fp32 global) -> xs[n][c] bf16 transposed, b128 LDS writes
  {
    const float* xg = x + (size_t)b * (DIMC * NPOS);
    for (int j = tid; j < NPOS * (DIMC / 8); j += 512) {   // 2352 jobs
      const int n  = j % 49;
      const int c0 = (j / 49) * 8;
      union { bf16x8 v; __hip_bfloat16 h[8]; } u;
      #pragma unroll
      for (int k = 0; k < 8; ++k)
        u.h[k] = f2b(xg[(c0 + k) * 49 + n]);
      *(bf16x8*)&xs[n * 392 + c0] = u.v;
    }
  }
  __syncthreads();   // bar1

  // ---- PA: qin[nq][c] = dw3x3 s2 p1 (local_q) + avgpool2. 384 thr, ALL indices
  //      compile-time -> xv[49] lives in registers (VGPR cap is 128 now).
  if (tid < 384) {
    const int c = tid;
    float xv[49];
    #pragma unroll
    for (int n = 0; n < 49; ++n) xv[n] = b2f(xs[n * 392 + c]);
    float wq[9];
    #pragma unroll
    for (int j = 0; j < 9; ++j) wq[j] = qlw[c * 9 + j];
    const float cb = qlb[c];
    #pragma unroll
    for (int oh = 0; oh < 4; ++oh) {
      #pragma unroll
      for (int ow = 0; ow < 4; ++ow) {
        float a = cb;
        #pragma unroll
        for (int kh = 0; kh < 3; ++kh) {
          const int ih = 2 * oh - 1 + kh;
          if (ih < 0 || ih > 6) continue;
          #pragma unroll
          for (int kwi = 0; kwi < 3; ++kwi) {
            const int iw = 2 * ow - 1 + kwi;
            if (iw < 0 || iw > 6) continue;
            a += wq[kh * 3 + kwi] * xv[ih * 7 + iw];
          }
        }
        if (oh < 3 && ow < 3)
          a += 0.25f * (xv[(2*oh)*7 + 2*ow] + xv[(2*oh)*7 + 2*ow + 1] +
                        xv[(2*oh+1)*7 + 2*ow] + xv[(2*oh+1)*7 + 2*ow + 1]);
        qin[(oh * 4 + ow) * 392 + c] = f2b(a);
      }
    }
  }
  __syncthreads();   // bar2

  // ---- kGEMM: wave=(nt=w&3, mtp=w>>2 -> 4 M-tiles), z read once/ks
  {
    const int nt  = wave & 3;
    const int mtp = wave >> 2;
    const int n   = nt * 16 + l15;
    f32x4 acc[4];
    #pragma unroll
    for (int i = 0; i < 4; ++i) acc[i] = fzero();
    for (int ks = 0; ks < 12; ++ks) {
      const int c0 = ks * 32 + quad * 8;
      bf16x8 z = (n < 49) ? ld8(&xs[n * 392 + c0]) : bzero();
      #pragma unroll
      for (int i = 0; i < 4; ++i) {
        bf16x8 a = ld8(&kwb[((mtp * 4 + i) * 16 + l15) * DIMC + c0]);
        acc[i] = __builtin_amdgcn_mfma_f32_16x16x32_bf16(a, z, acc[i], 0, 0, 0);
      }
    }
    #pragma unroll
    for (int i = 0; i < 4; ++i)
      #pragma unroll
      for (int r = 0; r < 4; ++r) {
        const int oc = (mtp * 4 + i) * 16 + quad * 4 + r;
        const float2 so = bnt[BN_K + oc];
        if (n < 49) kt[n * 136 + oc] = f2b(acc[i][r] * so.x + so.y);
      }
  }

  // ---- qGEMM: wave = M-tile (head). qsm[h][nq][kd 0..15] (no pad cols)
  {
    const int mt = wave;
    f32x4 acc = fzero();
    for (int ks = 0; ks < 12; ++ks) {
      const int c0 = ks * 32 + quad * 8;
      bf16x8 bv = ld8(&qin[l15 * 392 + c0]);
      bf16x8 av = ld8(&qpwb[(mt * 16 + l15) * DIMC + c0]);
      acc = __builtin_amdgcn_mfma_f32_16x16x32_bf16(av, bv, acc, 0, 0, 0);
    }
    #pragma unroll
    for (int r = 0; r < 4; ++r) {
      const int oc = mt * 16 + quad * 4 + r;
      const float2 so = bnt[BN_Q + oc];
      qsm[mt * 256 + l15 * 16 + (oc & 15)] = f2b(acc[r] * so.x + so.y);
    }
  }
  __syncthreads();   // bar3 — kt, qsm ready; qin dead

  // ---- PD: head h = wave; logits, softmax; attnS over dead qin (swizzled)
  {
    const int h = wave;
    bf16x8 av = (quad < 2) ? ld8(&qsm[h * 256 + l15 * 16 + quad * 8]) : bzero();
    float p[4][4];
    #pragma unroll
    for (int t = 0; t < 4; ++t) {
      bf16x8 bv = (quad < 2) ? ld8(&kt[(t * 16 + l15) * 136 + h * 16 + quad * 8]) : bzero();
      f32x4 lg = __builtin_amdgcn_mfma_f32_16x16x32_bf16(av, bv, fzero(), 0, 0, 0);
      #pragma unroll
      for (int r = 0; r < 4; ++r) {
        const int nq = quad * 4 + r;
        const int nk = t * 16 + l15;
        float val = -30000.f;
        if (nk < 49) val = lg[r] * 0.25f + ab[h * n_off + bidx[nq * 49 + nk]];
        p[t][r] = val;
      }
    }
    #pragma unroll
    for (int r = 0; r < 4; ++r) {
      float m = fmaxf(fmaxf(p[0][r], p[1][r]), fmaxf(p[2][r], p[3][r]));
      m = fmaxf(m, __shfl_xor(m, 1));
      m = fmaxf(m, __shfl_xor(m, 2));
      m = fmaxf(m, __shfl_xor(m, 4));
      m = fmaxf(m, __shfl_xor(m, 8));
      float e[4], sum = 0.f;
      #pragma unroll
      for (int t = 0; t < 4; ++t) { e[t] = __expf(p[t][r] - m); sum += e[t]; }
      sum += __shfl_xor(sum, 1);
      sum += __shfl_xor(sum, 2);
      sum += __shfl_xor(sum, 4);
      sum += __shfl_xor(sum, 8);
      const float inv = 1.f / sum;
      #pragma unroll
      for (int t = 0; t < 4; ++t) p[t][r] = e[t] * inv;   // exactly 0 for nk>=49
    }
    #pragma unroll
    for (int r = 0; r < 4; ++r) {
      const int nq = quad * 4 + r;
      #pragma unroll
      for (int t = 0; t < 4; ++t) {
        const int nk = t * 16 + l15;
        attnS[h * 1024 + nq * 64 + (nk ^ ((nq & 7) << 3))] = f2b(p[t][r]);
      }
    }
  }
  __syncthreads();   // bar4 — attnS ready; kt/qsm dead (vsm may overlay)

  // ================= v passes: 4 x 128 ch =================
  float res[4][4];   // [pass][r] — relu(xa+vloc), held in regs until xs dies
  #pragma unroll
  for (int p = 0; p < 4; ++p) {
    // -- vGEMM pass p: wave=(nt=w&3, mg=w>>2 -> 4 M-tiles), retire -> vsm (swz)
    {
      const int nt = wave & 3;
      const int mg = wave >> 2;
      const int n  = nt * 16 + l15;
      f32x4 acc[4];
      #pragma unroll
      for (int i = 0; i < 4; ++i) acc[i] = fzero();
      for (int ks = 0; ks < 12; ++ks) {
        const int c0 = ks * 32 + quad * 8;
        bf16x8 z = (n < 49) ? ld8(&xs[n * 392 + c0]) : bzero();
        #pragma unroll
        for (int i = 0; i < 4; ++i) {
          bf16x8 a = ld8(&vwb[(p * 128 + (mg * 4 + i) * 16 + l15) * DIMC + c0]);
          acc[i] = __builtin_amdgcn_mfma_f32_16x16x32_bf16(a, z, acc[i], 0, 0, 0);
        }
      }
      #pragma unroll
      for (int i = 0; i < 4; ++i)
        #pragma unroll
        for (int r = 0; r < 4; ++r) {
          const int chl = (mg * 4 + i) * 16 + quad * 4 + r;
          const float2 so = bnt[BN_V + p * 128 + chl];
          // all n incl. pads (finite) — PV multiplies pads by attn==0
          vsm[chl * 64 + (n ^ ((chl & 7) << 3))] = f2b(acc[i][r] * so.x + so.y);
        }
    }
    __syncthreads();   // barA — vsm pass p ready

    // -- fused v_local + PV: wave owns 16 ch (mt = wave); lane: ch=quad*4+r, pos=l15
    {
      const int pos = l15, oh = pos >> 2, ow = pos & 3;
      float vloc[4];
      #pragma unroll
      for (int r = 0; r < 4; ++r) {
        const int chl = wave * 16 + quad * 4 + r;
        const int gch = p * 128 + chl;
        float a = 0.f;
        #pragma unroll
        for (int kh = 0; kh < 3; ++kh) {
          #pragma unroll
          for (int kwi = 0; kwi < 3; ++kwi) {
            const int ih = 2 * oh - 1 + kh;
            const int iw = 2 * ow - 1 + kwi;
            const bool ok = ((unsigned)ih <= 6u) && ((unsigned)iw <= 6u);
            const int e = ok ? (ih * 7 + iw) : 0;
            const float tap = b2f(vsm[chl * 64 + (e ^ ((chl & 7) << 3))]);
            a += ok ? vlw[gch * 9 + kh * 3 + kwi] * tap : 0.f;
          }
        }
        const float2 so = bnt[BN_VL + gch];
        vloc[r] = a * so.x + so.y;
      }
      const int h = p * 2 + (wave >> 2);
      f32x4 pacc = fzero();
      #pragma unroll
      for (int ks = 0; ks < 2; ++ks) {
        const int k0 = ks * 32 + quad * 8;
        const int arow = wave * 16 + l15;
        bf16x8 av = ld8(&vsm[arow * 64 + (k0 ^ ((arow & 7) << 3))]);
        bf16x8 bv = ld8(&attnS[h * 1024 + l15 * 64 + (k0 ^ ((l15 & 7) << 3))]);
        pacc = __builtin_amdgcn_mfma_f32_16x16x32_bf16(av, bv, pacc, 0, 0, 0);
      }
      #pragma unroll
      for (int r = 0; r < 4; ++r)
        res[p][r] = fmaxf(pacc[r] + vloc[r], 0.f);
    }

    // after last pass's barA, xs is dead -> write rout (overlays xs)
    if (p == 3) {
      #pragma unroll
      for (int pp = 0; pp < 4; ++pp)
        #pragma unroll
        for (int r = 0; r < 4; ++r) {
          const int gch = pp * 128 + wave * 16 + quad * 4 + r;
          rout[l15 * 520 + gch] = f2b(res[pp][r]);
        }
    }
    __syncthreads();   // barB — vsm reusable / (p==3) rout ready
  }

  // ---- PF: proj GEMM — 24 M-tiles over 8 waves (3 each)
  {
    const int mt0 = wave * 3;
    f32x4 acc[3];
    #pragma unroll
    for (int t = 0; t < 3; ++t) acc[t] = fzero();
    for (int ks = 0; ks < 16; ++ks) {
      const int c0 = ks * 32 + quad * 8;
      bf16x8 bv = ld8(&rout[l15 * 520 + c0]);
      #pragma unroll
      for (int t = 0; t < 3; ++t) {
        bf16x8 av = ld8(&pwb[((mt0 + t) * 16 + l15) * DHC + c0]);
        acc[t] = __builtin_amdgcn_mfma_f32_16x16x32_bf16(av, bv, acc[t], 0, 0, 0);
      }
    }
    float* outb = out + (size_t)b * (OUTC * 16);
    #pragma unroll
    for (int t = 0; t < 3; ++t)
      #pragma unroll
      for (int r = 0; r < 4; ++r) {
        const int oc = (mt0 + t) * 16 + quad * 4 + r;
        const float2 so = bnt[BN_P + oc];
        outb[oc * 16 + l15] = acc[t][r] * so.x + so.y;
      }
  }
}

extern "C" void kernel_launch(void* const* d_in, const int* in_sizes, int n_in,
                              void* d_out, int out_size, void* d_ws, size_t ws_size,
                              hipStream_t stream) {
  const float* x    = (const float*)d_in[0];
  const float* qlw  = (const float*)d_in[1];
  const float* qlb  = (const float*)d_in[2];
  const float* qpw  = (const float*)d_in[3];
  const float* qpb  = (const float*)d_in[4];
  const float* qbn  = (const float*)d_in[5];
  const float* kw   = (const float*)d_in[6];
  const float* kb   = (const float*)d_in[7];
  const float* kbn  = (const float*)d_in[8];
  const float* vw   = (const float*)d_in[9];
  const float* vb   = (const float*)d_in[10];
  const float* vbn  = (const float*)d_in[11];
  const float* vlw  = (const float*)d_in[12];
  const float* vlb  = (const float*)d_in[13];
  const float* vlbn = (const float*)d_in[14];
  const float* pw   = (const float*)d_in[15];
  const float* pb   = (const float*)d_in[16];
  const float* pbn  = (const float*)d_in[17];
  const float* ab   = (const float*)d_in[18];
  const int*   bidx = (const int*)d_in[19];
  const int n_off = in_sizes[18] / 8;
  const int Bn = in_sizes[0] / (DIMC * NPOS);   // 2048

  __hip_bfloat16* wsb = (__hip_bfloat16*)d_ws;  // 983,040 B weights + 13,312 B BN table

  prep_weights<<<480, 256, 0, stream>>>(kw, vw, qpw, pw,
                                        kb, kbn, qpb, qbn, vb, vbn,
                                        vlb, vlbn, pb, pbn, wsb);
  attn4d_kernel<<<Bn, 512, 0, stream>>>(x, qlw, qlb, vlw, ab, bidx,
                                        wsb, n_off, (float*)d_out);
}

// Round 4
// 591.273 us; speedup vs baseline: 1.8398x; 1.8398x over previous
//
#include <hip/hip_runtime.h>
#include <hip/hip_bf16.h>

// Attention4DDownsample — fused, one workgroup per batch element.
// R8 = R5 structure (measured 400us, 5 barriers) minus its scratch sources.
// Key finding (R5-R7 counters): total VGPR budget 128 splits ~64 arch + ~64 AGPR;
// any phase with >~55 arch-live VALU values spills. Fixes:
//  - PA: rolling 3x7 window (~30 arch live) instead of xv[49] (R5's spill source)
//  - P0: bf16x8 built via static element inserts (no union/alloca)
//  - abf: prep pre-gathers ab[h][bidx[nq][nk]] -> dense f32 table (kills dependent
//    gather chains in PD)
//  - BN folded to float2 table in ws (prep kernel)
// MFMA accumulators (kGEMM 16, vGEMM 64, PF 12) live in AGPRs - not arch budget.

#define DIMC 384
#define NPOS 49
#define NHKD 128
#define DHC  512
#define OUTC 384

// ws bf16 weight offsets (elements)
#define OFF_KW  0
#define OFF_VW  49152
#define OFF_QPW 245760
#define OFF_PW  294912
#define W_TOT   491520
// BN fold table (float2, after W_TOT bf16 elems): k,q,v,vl,p
#define BN_K  0
#define BN_Q  128
#define BN_V  256
#define BN_VL 768
#define BN_P  1280
#define BN_TOT 1664
// abf table (f32, after BN table): [8][16*49] gathered bias
#define ABF_ELEMS (8 * 784)

// LDS (bf16 element offsets), total 38,152 elems = 76,304 B (2 blocks/CU)
#define XS_OFF   0        // xs [49][392]; vsm 8 x [32][72] overlays after bar3
#define KT_OFF   19208    // kt [64][136] (rows<49 valid); rout [16][520] overlays after bar4
#define QSM_OFF  27912    // qsm [8][16][16]
#define QIN_OFF  29960    // qin [16][392]; attnS [8][16][64] (swz) overlays after bar3
#define SMEM_ELEMS 38152

typedef __attribute__((ext_vector_type(8))) __bf16 bf16x8;
typedef __attribute__((ext_vector_type(4))) float f32x4;

static __device__ __forceinline__ __hip_bfloat16 f2b(float x) { return __float2bfloat16(x); }
static __device__ __forceinline__ float b2f(__hip_bfloat16 x) { return __bfloat162float(x); }
static __device__ __forceinline__ bf16x8 ld8(const __hip_bfloat16* p) { return *(const bf16x8*)p; }
static __device__ __forceinline__ f32x4 fzero() {
  f32x4 z; z[0] = 0.f; z[1] = 0.f; z[2] = 0.f; z[3] = 0.f; return z;
}
static __device__ __forceinline__ bf16x8 bzero() {
  bf16x8 z;
  #pragma unroll
  for (int j = 0; j < 8; ++j) z[j] = (__bf16)0.0f;
  return z;
}

// ---------------- prep: weights->bf16, BN fold->float2, bias gather->abf ----------------
__global__ void prep_weights(const float* __restrict__ kw, const float* __restrict__ vw,
                             const float* __restrict__ qpw, const float* __restrict__ pw,
                             const float* __restrict__ kb,  const float* __restrict__ kbn,
                             const float* __restrict__ qpb, const float* __restrict__ qbn,
                             const float* __restrict__ vb,  const float* __restrict__ vbn,
                             const float* __restrict__ vlb, const float* __restrict__ vlbn,
                             const float* __restrict__ pb,  const float* __restrict__ pbn,
                             const float* __restrict__ ab,  const int* __restrict__ bidx,
                             int n_off,
                             __hip_bfloat16* __restrict__ wsb) {
  const int gid = blockIdx.x * blockDim.x + threadIdx.x;
  const int stride = gridDim.x * blockDim.x;
  for (int i = gid; i < W_TOT; i += stride) {
    float v;
    if (i < OFF_VW)       v = kw[i - OFF_KW];
    else if (i < OFF_QPW) v = vw[i - OFF_VW];
    else if (i < OFF_PW)  v = qpw[i - OFF_QPW];
    else                  v = pw[i - OFF_PW];
    wsb[i] = f2b(v);
  }
  float2* bnt = (float2*)(wsb + W_TOT);
  for (int i = gid; i < BN_TOT; i += stride) {
    const float *bn, *cb; int ch, C;
    if (i < BN_Q)        { bn = kbn;  cb = kb;  ch = i;         C = NHKD; }
    else if (i < BN_V)   { bn = qbn;  cb = qpb; ch = i - BN_Q;  C = NHKD; }
    else if (i < BN_VL)  { bn = vbn;  cb = vb;  ch = i - BN_V;  C = DHC;  }
    else if (i < BN_P)   { bn = vlbn; cb = vlb; ch = i - BN_VL; C = DHC;  }
    else                 { bn = pbn;  cb = pb;  ch = i - BN_P;  C = OUTC; }
    const float g = bn[ch], be = bn[C + ch], mu = bn[2*C + ch], va = bn[3*C + ch];
    const float s = g * rsqrtf(va + 1e-5f);
    bnt[i] = make_float2(s, be + (cb[ch] - mu) * s);
  }
  float* abf = (float*)((char*)bnt + BN_TOT * 8);
  for (int i = gid; i < ABF_ELEMS; i += stride) {
    const int h = i / 784, j = i - h * 784;
    abf[i] = ab[h * n_off + bidx[j]];
  }
}

// ---------------- main fused kernel ----------------
__global__ __launch_bounds__(512, 4) void attn4d_kernel(
    const float* __restrict__ x,
    const float* __restrict__ qlw, const float* __restrict__ qlb,
    const float* __restrict__ vlw,
    const __hip_bfloat16* __restrict__ wsb,
    float* __restrict__ out)
{
  __shared__ __align__(16) __hip_bfloat16 smem[SMEM_ELEMS];
  __hip_bfloat16* xs    = smem + XS_OFF;     // [49][392]
  __hip_bfloat16* vsm   = smem + XS_OFF;     // 8 x [32][72], overlays xs post-bar3
  __hip_bfloat16* kt    = smem + KT_OFF;     // [64][136]
  __hip_bfloat16* rout  = smem + KT_OFF;     // [16][520], overlays kt post-bar4
  __hip_bfloat16* qsm   = smem + QSM_OFF;    // [8][16][16]
  __hip_bfloat16* qin   = smem + QIN_OFF;    // [16][392]
  __hip_bfloat16* attnS = smem + QIN_OFF;    // [8][16][64] swz, overlays qin post-bar3

  const __hip_bfloat16* kwb  = wsb + OFF_KW;
  const __hip_bfloat16* vwb  = wsb + OFF_VW;
  const __hip_bfloat16* qpwb = wsb + OFF_QPW;
  const __hip_bfloat16* pwb  = wsb + OFF_PW;
  const float2* bnt = (const float2*)(wsb + W_TOT);
  const float*  abf = (const float*)((const char*)bnt + BN_TOT * 8);

  const int tid  = threadIdx.x;
  const int lane = tid & 63;
  const int wave = tid >> 6;     // 0..7
  const int quad = lane >> 4;    // 0..3
  const int l15  = lane & 15;
  const int b    = blockIdx.x;

  // ---- P0: stage x[b] (fp32 global) -> xs[n][c] bf16 transposed, b128 LDS writes
  {
    const float* xg = x + (size_t)b * (DIMC * NPOS);
    for (int j = tid; j < NPOS * (DIMC / 8); j += 512) {   // 2352 jobs
      const int n  = j % 49;
      const int c0 = (j / 49) * 8;
      bf16x8 v;
      #pragma unroll
      for (int k = 0; k < 8; ++k)
        v[k] = (__bf16)(xg[(c0 + k) * 49 + n]);
      *(bf16x8*)&xs[n * 392 + c0] = v;
    }
  }
  __syncthreads();   // bar1

  // ---- PA: qin[nq][c] = dw3x3 s2 p1 + avgpool2. Rolling 3x7 window, ~30 arch live.
  if (tid < 384) {
    const int c = tid;
    float wq[9];
    #pragma unroll
    for (int j = 0; j < 9; ++j) wq[j] = qlw[c * 9 + j];
    const float cb = qlb[c];
    #pragma unroll
    for (int oh = 0; oh < 4; ++oh) {
      float w[3][7];   // rows 2oh-1, 2oh, 2oh+1 (zeros when out of range)
      #pragma unroll
      for (int i = 0; i < 7; ++i) {
        w[0][i] = (oh > 0) ? b2f(xs[((2*oh - 1) * 7 + i) * 392 + c]) : 0.f;
        w[1][i] = b2f(xs[((2*oh) * 7 + i) * 392 + c]);
        w[2][i] = (oh < 3) ? b2f(xs[((2*oh + 1) * 7 + i) * 392 + c]) : 0.f;
      }
      #pragma unroll
      for (int ow = 0; ow < 4; ++ow) {
        float a = cb;
        #pragma unroll
        for (int kh = 0; kh < 3; ++kh) {
          #pragma unroll
          for (int kwi = 0; kwi < 3; ++kwi) {
            const int iw = 2 * ow - 1 + kwi;
            if (iw < 0 || iw > 6) continue;
            a += wq[kh * 3 + kwi] * w[kh][iw];   // invalid ih rows are zeros
          }
        }
        if (oh < 3 && ow < 3)
          a += 0.25f * (w[1][2*ow] + w[1][2*ow + 1] + w[2][2*ow] + w[2][2*ow + 1]);
        qin[(oh * 4 + ow) * 392 + c] = f2b(a);
      }
    }
  }
  __syncthreads();   // bar2

  // ================= MEGA phase: kGEMM + qGEMM + vGEMM =================

  // -- k GEMM: wave = M-tile, 4 N-tiles, K=384 -> kt (16 AGPR)
  {
    const int mt = wave;
    f32x4 acc[4];
    #pragma unroll
    for (int nt = 0; nt < 4; ++nt) acc[nt] = fzero();
    for (int ks = 0; ks < 12; ++ks) {
      const int c0 = ks * 32 + quad * 8;
      bf16x8 a = ld8(&kwb[(mt * 16 + l15) * DIMC + c0]);
      bf16x8 z[4];
      #pragma unroll
      for (int nt = 0; nt < 3; ++nt) z[nt] = ld8(&xs[(nt * 16 + l15) * 392 + c0]);
      z[3] = (l15 == 0) ? ld8(&xs[48 * 392 + c0]) : bzero();
      #pragma unroll
      for (int nt = 0; nt < 4; ++nt)
        acc[nt] = __builtin_amdgcn_mfma_f32_16x16x32_bf16(a, z[nt], acc[nt], 0, 0, 0);
    }
    #pragma unroll
    for (int r = 0; r < 4; ++r) {
      const int oc = mt * 16 + quad * 4 + r;
      const float2 so = bnt[BN_K + oc];
      #pragma unroll
      for (int nt = 0; nt < 4; ++nt) {
        const int n = nt * 16 + l15;
        if (n < 49) kt[n * 136 + oc] = f2b(acc[nt][r] * so.x + so.y);
        // rows 49..63 stale garbage: only feed masked nk>=49 logits (discarded)
      }
    }
  }

  // -- q GEMM: wave = M-tile (head) -> qsm[h][nq][kd]
  {
    const int mt = wave;
    f32x4 acc = fzero();
    for (int ks = 0; ks < 12; ++ks) {
      const int c0 = ks * 32 + quad * 8;
      bf16x8 bv = ld8(&qin[l15 * 392 + c0]);
      bf16x8 av = ld8(&qpwb[(mt * 16 + l15) * DIMC + c0]);
      acc = __builtin_amdgcn_mfma_f32_16x16x32_bf16(av, bv, acc, 0, 0, 0);
    }
    #pragma unroll
    for (int r = 0; r < 4; ++r) {
      const int oc = mt * 16 + quad * 4 + r;
      const float2 so = bnt[BN_Q + oc];
      qsm[mt * 256 + l15 * 16 + (oc & 15)] = f2b(acc[r] * so.x + so.y);
    }
  }

  // -- v GEMM: wave owns ch {32w..+31} and {256+32w..+31}; 64 AGPR accs
  f32x4 va[2][2][4];   // [pass][mt][nt]
  #pragma unroll
  for (int p = 0; p < 2; ++p)
    #pragma unroll
    for (int mt = 0; mt < 2; ++mt)
      #pragma unroll
      for (int nt = 0; nt < 4; ++nt) va[p][mt][nt] = fzero();
  {
    const int chb = wave * 32;
    for (int ks = 0; ks < 12; ++ks) {
      const int c0 = ks * 32 + quad * 8;
      bf16x8 z[4];
      #pragma unroll
      for (int nt = 0; nt < 3; ++nt) z[nt] = ld8(&xs[(nt * 16 + l15) * 392 + c0]);
      z[3] = (l15 == 0) ? ld8(&xs[48 * 392 + c0]) : bzero();
      #pragma unroll
      for (int p = 0; p < 2; ++p) {
        #pragma unroll
        for (int mt = 0; mt < 2; ++mt) {
          bf16x8 a = ld8(&vwb[(p * 256 + chb + mt * 16 + l15) * DIMC + c0]);
          #pragma unroll
          for (int nt = 0; nt < 4; ++nt)
            va[p][mt][nt] = __builtin_amdgcn_mfma_f32_16x16x32_bf16(a, z[nt], va[p][mt][nt], 0, 0, 0);
        }
      }
    }
  }
  __syncthreads();   // bar3 — xs dead; kt/qsm ready; qin dead

  // ---- write vsm pass 0 (own wave's block, overlays dead xs)
  {
    __hip_bfloat16* vbw_ = vsm + wave * 2304;
    #pragma unroll
    for (int mt = 0; mt < 2; ++mt)
      #pragma unroll
      for (int r = 0; r < 4; ++r) {
        const int chl = mt * 16 + quad * 4 + r;
        const float2 so = bnt[BN_V + wave * 32 + chl];
        #pragma unroll
        for (int nt = 0; nt < 4; ++nt)
          vbw_[chl * 72 + nt * 16 + l15] = f2b(va[0][mt][nt][r] * so.x + so.y);
        // n 49..63 finite pads: PV multiplies them by attn==0
      }
  }

  // ---- PD: QK^T*scale + abf bias, softmax -> attnS (XOR-swizzled)
  {
    const int h = wave;
    bf16x8 av = (quad < 2) ? ld8(&qsm[h * 256 + l15 * 16 + quad * 8]) : bzero();
    float p[4][4];
    #pragma unroll
    for (int t = 0; t < 4; ++t) {
      bf16x8 bv = (quad < 2) ? ld8(&kt[(t * 16 + l15) * 136 + h * 16 + quad * 8]) : bzero();
      f32x4 lg = __builtin_amdgcn_mfma_f32_16x16x32_bf16(av, bv, fzero(), 0, 0, 0);
      #pragma unroll
      for (int r = 0; r < 4; ++r) {
        const int nq = quad * 4 + r;
        const int nk = t * 16 + l15;
        float val = -30000.f;
        if (nk < 49) val = lg[r] * 0.25f + abf[h * 784 + nq * 49 + nk];
        p[t][r] = val;
      }
    }
    #pragma unroll
    for (int r = 0; r < 4; ++r) {
      float m = fmaxf(fmaxf(p[0][r], p[1][r]), fmaxf(p[2][r], p[3][r]));
      m = fmaxf(m, __shfl_xor(m, 1));
      m = fmaxf(m, __shfl_xor(m, 2));
      m = fmaxf(m, __shfl_xor(m, 4));
      m = fmaxf(m, __shfl_xor(m, 8));
      float e[4], sum = 0.f;
      #pragma unroll
      for (int t = 0; t < 4; ++t) { e[t] = __expf(p[t][r] - m); sum += e[t]; }
      sum += __shfl_xor(sum, 1);
      sum += __shfl_xor(sum, 2);
      sum += __shfl_xor(sum, 4);
      sum += __shfl_xor(sum, 8);
      const float inv = 1.f / sum;
      #pragma unroll
      for (int t = 0; t < 4; ++t) p[t][r] = e[t] * inv;   // exactly 0 for nk>=49
    }
    #pragma unroll
    for (int r = 0; r < 4; ++r) {
      const int nq = quad * 4 + r;
      #pragma unroll
      for (int t = 0; t < 4; ++t) {
        const int nk = t * 16 + l15;
        attnS[h * 1024 + nq * 64 + (nk ^ ((nq & 7) << 3))] = f2b(p[t][r]);
      }
    }
  }
  __syncthreads();   // bar4 — attnS ready; kt dead (rout may overlay)

  // ================= v-path: wave-private, NO barriers =================
  #pragma unroll
  for (int p = 0; p < 2; ++p) {
    if (p == 1) {   // write vsm pass 1 (own block; pass-0 consumers were same-wave)
      __hip_bfloat16* vbw_ = vsm + wave * 2304;
      #pragma unroll
      for (int mt = 0; mt < 2; ++mt)
        #pragma unroll
        for (int r = 0; r < 4; ++r) {
          const int chl = mt * 16 + quad * 4 + r;
          const float2 so = bnt[BN_V + 256 + wave * 32 + chl];
          #pragma unroll
          for (int nt = 0; nt < 4; ++nt)
            vbw_[chl * 72 + nt * 16 + l15] = f2b(va[1][mt][nt][r] * so.x + so.y);
        }
    }

    // v_local: lane = (half, cl); 8 positions per lane; row cached in rv[7]
    {
      const int cl   = lane & 31;
      const int half = lane >> 5;
      const int gch  = p * 256 + wave * 32 + cl;
      const __hip_bfloat16* vrow = vsm + wave * 2304 + cl * 72;
      bf16x8 rv[7];
      #pragma unroll
      for (int t = 0; t < 7; ++t) rv[t] = ld8(vrow + t * 8);
      float wv[9];
      #pragma unroll
      for (int j = 0; j < 9; ++j) wv[j] = vlw[gch * 9 + j];
      const float2 so = bnt[BN_VL + gch];
      #pragma unroll
      for (int pp = 0; pp < 8; ++pp) {
        const int pos = half * 8 + pp;
        const int oh = pos >> 2, ow = pos & 3;
        float a = 0.f;
        #pragma unroll
        for (int kh = 0; kh < 3; ++kh) {
          const int ih = 2 * oh - 1 + kh;
          if (ih < 0 || ih > 6) continue;
          #pragma unroll
          for (int kwi = 0; kwi < 3; ++kwi) {
            const int iw = 2 * ow - 1 + kwi;
            if (iw < 0 || iw > 6) continue;
            const int e = ih * 7 + iw;      // compile-time after unroll
            a += wv[kh * 3 + kwi] * (float)rv[e >> 3][e & 7];
          }
        }
        rout[pos * 520 + gch] = f2b(a * so.x + so.y);
      }
    }

    // PV (head h = 4p + w/2): 2 M-tiles over own 32 ch; rout = relu(xa + vloc)
    {
      const int h = p * 4 + (wave >> 1);
      const __hip_bfloat16* vbw_ = vsm + wave * 2304;
      #pragma unroll
      for (int mt = 0; mt < 2; ++mt) {
        f32x4 acc = fzero();
        #pragma unroll
        for (int ks = 0; ks < 2; ++ks) {
          const int k0 = ks * 32 + quad * 8;
          bf16x8 avv = ld8(&vbw_[(mt * 16 + l15) * 72 + k0]);                    // A[ch][nk]
          bf16x8 bvv = ld8(&attnS[h * 1024 + l15 * 64 + (k0 ^ ((l15 & 7) << 3))]); // B[nq][nk]
          acc = __builtin_amdgcn_mfma_f32_16x16x32_bf16(avv, bvv, acc, 0, 0, 0);
        }
        #pragma unroll
        for (int r = 0; r < 4; ++r) {
          const int gch = p * 256 + wave * 32 + mt * 16 + quad * 4 + r;
          const int ad = l15 * 520 + gch;
          const float val = acc[r] + b2f(rout[ad]);
          rout[ad] = f2b(fmaxf(val, 0.f));
        }
      }
    }
  }
  __syncthreads();   // bar5 — rout complete

  // ---- PF: proj GEMM — 24 M-tiles over 8 waves (3 each)
  {
    const int mt0 = wave * 3;
    f32x4 acc[3];
    #pragma unroll
    for (int t = 0; t < 3; ++t) acc[t] = fzero();
    for (int ks = 0; ks < 16; ++ks) {
      const int c0 = ks * 32 + quad * 8;
      bf16x8 bv = ld8(&rout[l15 * 520 + c0]);
      #pragma unroll
      for (int t = 0; t < 3; ++t) {
        bf16x8 av = ld8(&pwb[((mt0 + t) * 16 + l15) * DHC + c0]);
        acc[t] = __builtin_amdgcn_mfma_f32_16x16x32_bf16(av, bv, acc[t], 0, 0, 0);
      }
    }
    float* outb = out + (size_t)b * (OUTC * 16);
    #pragma unroll
    for (int t = 0; t < 3; ++t)
      #pragma unroll
      for (int r = 0; r < 4; ++r) {
        const int oc = (mt0 + t) * 16 + quad * 4 + r;
        const float2 so = bnt[BN_P + oc];
        outb[oc * 16 + l15] = acc[t][r] * so.x + so.y;
      }
  }
}

extern "C" void kernel_launch(void* const* d_in, const int* in_sizes, int n_in,
                              void* d_out, int out_size, void* d_ws, size_t ws_size,
                              hipStream_t stream) {
  const float* x    = (const float*)d_in[0];
  const float* qlw  = (const float*)d_in[1];
  const float* qlb  = (const float*)d_in[2];
  const float* qpw  = (const float*)d_in[3];
  const float* qpb  = (const float*)d_in[4];
  const float* qbn  = (const float*)d_in[5];
  const float* kw   = (const float*)d_in[6];
  const float* kb   = (const float*)d_in[7];
  const float* kbn  = (const float*)d_in[8];
  const float* vw   = (const float*)d_in[9];
  const float* vb   = (const float*)d_in[10];
  const float* vbn  = (const float*)d_in[11];
  const float* vlw  = (const float*)d_in[12];
  const float* vlb  = (const float*)d_in[13];
  const float* vlbn = (const float*)d_in[14];
  const float* pw   = (const float*)d_in[15];
  const float* pb   = (const float*)d_in[16];
  const float* pbn  = (const float*)d_in[17];
  const float* ab   = (const float*)d_in[18];
  const int*   bidx = (const int*)d_in[19];
  const int n_off = in_sizes[18] / 8;
  const int Bn = in_sizes[0] / (DIMC * NPOS);   // 2048

  __hip_bfloat16* wsb = (__hip_bfloat16*)d_ws;  // 983 KB weights + 13 KB BN + 25 KB abf

  prep_weights<<<480, 256, 0, stream>>>(kw, vw, qpw, pw,
                                        kb, kbn, qpb, qbn, vb, vbn,
                                        vlb, vlbn, pb, pbn, ab, bidx, n_off, wsb);
  attn4d_kernel<<<Bn, 512, 0, stream>>>(x, qlw, qlb, vlw, wsb, (float*)d_out);
}

// Round 5
// 586.289 us; speedup vs baseline: 1.8555x; 1.0085x over previous
//
#include <hip/hip_runtime.h>
#include <hip/hip_bf16.h>

// Attention4DDownsample — fused, one workgroup per batch element.
// R9 = R8 body, ONE change: amdgpu_waves_per_eu(4, 4)  (min AND max pinned).
// R5-R8 all reported VGPR_Count=64 with massive scratch traffic (WRITE_SIZE up
// to 639 MB vs 51 MB needed): __launch_bounds__(512,4) / amdgpu_waves_per_eu(4)
// only set the MINIMUM of the waves-per-EU range -> allocator still targets 8
// waves/EU = 64 VGPR budget and spills to reach an occupancy the 76.8 KB LDS
// (2 blocks/CU = 4 waves/EU) can never provide. Pinning max=4 frees 128 VGPRs;
// R8's worst live set (64 acc f32 + ~50 arch) fits.

#define DIMC 384
#define NPOS 49
#define NHKD 128
#define DHC  512
#define OUTC 384

// ws bf16 weight offsets (elements)
#define OFF_KW  0
#define OFF_VW  49152
#define OFF_QPW 245760
#define OFF_PW  294912
#define W_TOT   491520
// BN fold table (float2, after W_TOT bf16 elems): k,q,v,vl,p
#define BN_K  0
#define BN_Q  128
#define BN_V  256
#define BN_VL 768
#define BN_P  1280
#define BN_TOT 1664
// abf table (f32, after BN table): [8][16*49] gathered bias
#define ABF_ELEMS (8 * 784)

// LDS (bf16 element offsets), total 38,152 elems = 76,304 B (2 blocks/CU)
#define XS_OFF   0        // xs [49][392]; vsm 8 x [32][72] overlays after bar3
#define KT_OFF   19208    // kt [64][136] (rows<49 valid); rout [16][520] overlays after bar4
#define QSM_OFF  27912    // qsm [8][16][16]
#define QIN_OFF  29960    // qin [16][392]; attnS [8][16][64] (swz) overlays after bar3
#define SMEM_ELEMS 38152

typedef __attribute__((ext_vector_type(8))) __bf16 bf16x8;
typedef __attribute__((ext_vector_type(4))) float f32x4;

static __device__ __forceinline__ __hip_bfloat16 f2b(float x) { return __float2bfloat16(x); }
static __device__ __forceinline__ float b2f(__hip_bfloat16 x) { return __bfloat162float(x); }
static __device__ __forceinline__ bf16x8 ld8(const __hip_bfloat16* p) { return *(const bf16x8*)p; }
static __device__ __forceinline__ f32x4 fzero() {
  f32x4 z; z[0] = 0.f; z[1] = 0.f; z[2] = 0.f; z[3] = 0.f; return z;
}
static __device__ __forceinline__ bf16x8 bzero() {
  bf16x8 z;
  #pragma unroll
  for (int j = 0; j < 8; ++j) z[j] = (__bf16)0.0f;
  return z;
}

// ---------------- prep: weights->bf16, BN fold->float2, bias gather->abf ----------------
__global__ void prep_weights(const float* __restrict__ kw, const float* __restrict__ vw,
                             const float* __restrict__ qpw, const float* __restrict__ pw,
                             const float* __restrict__ kb,  const float* __restrict__ kbn,
                             const float* __restrict__ qpb, const float* __restrict__ qbn,
                             const float* __restrict__ vb,  const float* __restrict__ vbn,
                             const float* __restrict__ vlb, const float* __restrict__ vlbn,
                             const float* __restrict__ pb,  const float* __restrict__ pbn,
                             const float* __restrict__ ab,  const int* __restrict__ bidx,
                             int n_off,
                             __hip_bfloat16* __restrict__ wsb) {
  const int gid = blockIdx.x * blockDim.x + threadIdx.x;
  const int stride = gridDim.x * blockDim.x;
  for (int i = gid; i < W_TOT; i += stride) {
    float v;
    if (i < OFF_VW)       v = kw[i - OFF_KW];
    else if (i < OFF_QPW) v = vw[i - OFF_VW];
    else if (i < OFF_PW)  v = qpw[i - OFF_QPW];
    else                  v = pw[i - OFF_PW];
    wsb[i] = f2b(v);
  }
  float2* bnt = (float2*)(wsb + W_TOT);
  for (int i = gid; i < BN_TOT; i += stride) {
    const float *bn, *cb; int ch, C;
    if (i < BN_Q)        { bn = kbn;  cb = kb;  ch = i;         C = NHKD; }
    else if (i < BN_V)   { bn = qbn;  cb = qpb; ch = i - BN_Q;  C = NHKD; }
    else if (i < BN_VL)  { bn = vbn;  cb = vb;  ch = i - BN_V;  C = DHC;  }
    else if (i < BN_P)   { bn = vlbn; cb = vlb; ch = i - BN_VL; C = DHC;  }
    else                 { bn = pbn;  cb = pb;  ch = i - BN_P;  C = OUTC; }
    const float g = bn[ch], be = bn[C + ch], mu = bn[2*C + ch], va = bn[3*C + ch];
    const float s = g * rsqrtf(va + 1e-5f);
    bnt[i] = make_float2(s, be + (cb[ch] - mu) * s);
  }
  float* abf = (float*)((char*)bnt + BN_TOT * 8);
  for (int i = gid; i < ABF_ELEMS; i += stride) {
    const int h = i / 784, j = i - h * 784;
    abf[i] = ab[h * n_off + bidx[j]];
  }
}

// ---------------- main fused kernel ----------------
__global__ __attribute__((amdgpu_flat_work_group_size(512, 512), amdgpu_waves_per_eu(4, 4)))
void attn4d_kernel(
    const float* __restrict__ x,
    const float* __restrict__ qlw, const float* __restrict__ qlb,
    const float* __restrict__ vlw,
    const __hip_bfloat16* __restrict__ wsb,
    float* __restrict__ out)
{
  __shared__ __align__(16) __hip_bfloat16 smem[SMEM_ELEMS];
  __hip_bfloat16* xs    = smem + XS_OFF;     // [49][392]
  __hip_bfloat16* vsm   = smem + XS_OFF;     // 8 x [32][72], overlays xs post-bar3
  __hip_bfloat16* kt    = smem + KT_OFF;     // [64][136]
  __hip_bfloat16* rout  = smem + KT_OFF;     // [16][520], overlays kt post-bar4
  __hip_bfloat16* qsm   = smem + QSM_OFF;    // [8][16][16]
  __hip_bfloat16* qin   = smem + QIN_OFF;    // [16][392]
  __hip_bfloat16* attnS = smem + QIN_OFF;    // [8][16][64] swz, overlays qin post-bar3

  const __hip_bfloat16* kwb  = wsb + OFF_KW;
  const __hip_bfloat16* vwb  = wsb + OFF_VW;
  const __hip_bfloat16* qpwb = wsb + OFF_QPW;
  const __hip_bfloat16* pwb  = wsb + OFF_PW;
  const float2* bnt = (const float2*)(wsb + W_TOT);
  const float*  abf = (const float*)((const char*)bnt + BN_TOT * 8);

  const int tid  = threadIdx.x;
  const int lane = tid & 63;
  const int wave = tid >> 6;     // 0..7
  const int quad = lane >> 4;    // 0..3
  const int l15  = lane & 15;
  const int b    = blockIdx.x;

  // ---- P0: stage x[b] (fp32 global) -> xs[n][c] bf16 transposed, b128 LDS writes
  {
    const float* xg = x + (size_t)b * (DIMC * NPOS);
    for (int j = tid; j < NPOS * (DIMC / 8); j += 512) {   // 2352 jobs
      const int n  = j % 49;
      const int c0 = (j / 49) * 8;
      bf16x8 v;
      #pragma unroll
      for (int k = 0; k < 8; ++k)
        v[k] = (__bf16)(xg[(c0 + k) * 49 + n]);
      *(bf16x8*)&xs[n * 392 + c0] = v;
    }
  }
  __syncthreads();   // bar1

  // ---- PA: qin[nq][c] = dw3x3 s2 p1 + avgpool2. Rolling 3x7 window, ~30 arch live.
  if (tid < 384) {
    const int c = tid;
    float wq[9];
    #pragma unroll
    for (int j = 0; j < 9; ++j) wq[j] = qlw[c * 9 + j];
    const float cb = qlb[c];
    #pragma unroll
    for (int oh = 0; oh < 4; ++oh) {
      float w[3][7];   // rows 2oh-1, 2oh, 2oh+1 (zeros when out of range)
      #pragma unroll
      for (int i = 0; i < 7; ++i) {
        w[0][i] = (oh > 0) ? b2f(xs[((2*oh - 1) * 7 + i) * 392 + c]) : 0.f;
        w[1][i] = b2f(xs[((2*oh) * 7 + i) * 392 + c]);
        w[2][i] = (oh < 3) ? b2f(xs[((2*oh + 1) * 7 + i) * 392 + c]) : 0.f;
      }
      #pragma unroll
      for (int ow = 0; ow < 4; ++ow) {
        float a = cb;
        #pragma unroll
        for (int kh = 0; kh < 3; ++kh) {
          #pragma unroll
          for (int kwi = 0; kwi < 3; ++kwi) {
            const int iw = 2 * ow - 1 + kwi;
            if (iw < 0 || iw > 6) continue;
            a += wq[kh * 3 + kwi] * w[kh][iw];   // invalid ih rows are zeros
          }
        }
        if (oh < 3 && ow < 3)
          a += 0.25f * (w[1][2*ow] + w[1][2*ow + 1] + w[2][2*ow] + w[2][2*ow + 1]);
        qin[(oh * 4 + ow) * 392 + c] = f2b(a);
      }
    }
  }
  __syncthreads();   // bar2

  // ================= MEGA phase: kGEMM + qGEMM + vGEMM =================

  // -- k GEMM: wave = M-tile, 4 N-tiles, K=384 -> kt
  {
    const int mt = wave;
    f32x4 acc[4];
    #pragma unroll
    for (int nt = 0; nt < 4; ++nt) acc[nt] = fzero();
    for (int ks = 0; ks < 12; ++ks) {
      const int c0 = ks * 32 + quad * 8;
      bf16x8 a = ld8(&kwb[(mt * 16 + l15) * DIMC + c0]);
      bf16x8 z[4];
      #pragma unroll
      for (int nt = 0; nt < 3; ++nt) z[nt] = ld8(&xs[(nt * 16 + l15) * 392 + c0]);
      z[3] = (l15 == 0) ? ld8(&xs[48 * 392 + c0]) : bzero();
      #pragma unroll
      for (int nt = 0; nt < 4; ++nt)
        acc[nt] = __builtin_amdgcn_mfma_f32_16x16x32_bf16(a, z[nt], acc[nt], 0, 0, 0);
    }
    #pragma unroll
    for (int r = 0; r < 4; ++r) {
      const int oc = mt * 16 + quad * 4 + r;
      const float2 so = bnt[BN_K + oc];
      #pragma unroll
      for (int nt = 0; nt < 4; ++nt) {
        const int n = nt * 16 + l15;
        if (n < 49) kt[n * 136 + oc] = f2b(acc[nt][r] * so.x + so.y);
        // rows 49..63 stale garbage: only feed masked nk>=49 logits (discarded)
      }
    }
  }

  // -- q GEMM: wave = M-tile (head) -> qsm[h][nq][kd]
  {
    const int mt = wave;
    f32x4 acc = fzero();
    for (int ks = 0; ks < 12; ++ks) {
      const int c0 = ks * 32 + quad * 8;
      bf16x8 bv = ld8(&qin[l15 * 392 + c0]);
      bf16x8 av = ld8(&qpwb[(mt * 16 + l15) * DIMC + c0]);
      acc = __builtin_amdgcn_mfma_f32_16x16x32_bf16(av, bv, acc, 0, 0, 0);
    }
    #pragma unroll
    for (int r = 0; r < 4; ++r) {
      const int oc = mt * 16 + quad * 4 + r;
      const float2 so = bnt[BN_Q + oc];
      qsm[mt * 256 + l15 * 16 + (oc & 15)] = f2b(acc[r] * so.x + so.y);
    }
  }

  // -- v GEMM: wave owns ch {32w..+31} and {256+32w..+31}; 64 f32 accs (fits in 128)
  f32x4 va[2][2][4];   // [pass][mt][nt]
  #pragma unroll
  for (int p = 0; p < 2; ++p)
    #pragma unroll
    for (int mt = 0; mt < 2; ++mt)
      #pragma unroll
      for (int nt = 0; nt < 4; ++nt) va[p][mt][nt] = fzero();
  {
    const int chb = wave * 32;
    for (int ks = 0; ks < 12; ++ks) {
      const int c0 = ks * 32 + quad * 8;
      bf16x8 z[4];
      #pragma unroll
      for (int nt = 0; nt < 3; ++nt) z[nt] = ld8(&xs[(nt * 16 + l15) * 392 + c0]);
      z[3] = (l15 == 0) ? ld8(&xs[48 * 392 + c0]) : bzero();
      #pragma unroll
      for (int p = 0; p < 2; ++p) {
        #pragma unroll
        for (int mt = 0; mt < 2; ++mt) {
          bf16x8 a = ld8(&vwb[(p * 256 + chb + mt * 16 + l15) * DIMC + c0]);
          #pragma unroll
          for (int nt = 0; nt < 4; ++nt)
            va[p][mt][nt] = __builtin_amdgcn_mfma_f32_16x16x32_bf16(a, z[nt], va[p][mt][nt], 0, 0, 0);
        }
      }
    }
  }
  __syncthreads();   // bar3 — xs dead; kt/qsm ready; qin dead

  // ---- write vsm pass 0 (own wave's block, overlays dead xs)
  {
    __hip_bfloat16* vbw_ = vsm + wave * 2304;
    #pragma unroll
    for (int mt = 0; mt < 2; ++mt)
      #pragma unroll
      for (int r = 0; r < 4; ++r) {
        const int chl = mt * 16 + quad * 4 + r;
        const float2 so = bnt[BN_V + wave * 32 + chl];
        #pragma unroll
        for (int nt = 0; nt < 4; ++nt)
          vbw_[chl * 72 + nt * 16 + l15] = f2b(va[0][mt][nt][r] * so.x + so.y);
        // n 49..63 finite pads: PV multiplies them by attn==0
      }
  }

  // ---- PD: QK^T*scale + abf bias, softmax -> attnS (XOR-swizzled)
  {
    const int h = wave;
    bf16x8 av = (quad < 2) ? ld8(&qsm[h * 256 + l15 * 16 + quad * 8]) : bzero();
    float p[4][4];
    #pragma unroll
    for (int t = 0; t < 4; ++t) {
      bf16x8 bv = (quad < 2) ? ld8(&kt[(t * 16 + l15) * 136 + h * 16 + quad * 8]) : bzero();
      f32x4 lg = __builtin_amdgcn_mfma_f32_16x16x32_bf16(av, bv, fzero(), 0, 0, 0);
      #pragma unroll
      for (int r = 0; r < 4; ++r) {
        const int nq = quad * 4 + r;
        const int nk = t * 16 + l15;
        float val = -30000.f;
        if (nk < 49) val = lg[r] * 0.25f + abf[h * 784 + nq * 49 + nk];
        p[t][r] = val;
      }
    }
    #pragma unroll
    for (int r = 0; r < 4; ++r) {
      float m = fmaxf(fmaxf(p[0][r], p[1][r]), fmaxf(p[2][r], p[3][r]));
      m = fmaxf(m, __shfl_xor(m, 1));
      m = fmaxf(m, __shfl_xor(m, 2));
      m = fmaxf(m, __shfl_xor(m, 4));
      m = fmaxf(m, __shfl_xor(m, 8));
      float e[4], sum = 0.f;
      #pragma unroll
      for (int t = 0; t < 4; ++t) { e[t] = __expf(p[t][r] - m); sum += e[t]; }
      sum += __shfl_xor(sum, 1);
      sum += __shfl_xor(sum, 2);
      sum += __shfl_xor(sum, 4);
      sum += __shfl_xor(sum, 8);
      const float inv = 1.f / sum;
      #pragma unroll
      for (int t = 0; t < 4; ++t) p[t][r] = e[t] * inv;   // exactly 0 for nk>=49
    }
    #pragma unroll
    for (int r = 0; r < 4; ++r) {
      const int nq = quad * 4 + r;
      #pragma unroll
      for (int t = 0; t < 4; ++t) {
        const int nk = t * 16 + l15;
        attnS[h * 1024 + nq * 64 + (nk ^ ((nq & 7) << 3))] = f2b(p[t][r]);
      }
    }
  }
  __syncthreads();   // bar4 — attnS ready; kt dead (rout may overlay)

  // ================= v-path: wave-private, NO barriers =================
  #pragma unroll
  for (int p = 0; p < 2; ++p) {
    if (p == 1) {   // write vsm pass 1 (own block; pass-0 consumers were same-wave)
      __hip_bfloat16* vbw_ = vsm + wave * 2304;
      #pragma unroll
      for (int mt = 0; mt < 2; ++mt)
        #pragma unroll
        for (int r = 0; r < 4; ++r) {
          const int chl = mt * 16 + quad * 4 + r;
          const float2 so = bnt[BN_V + 256 + wave * 32 + chl];
          #pragma unroll
          for (int nt = 0; nt < 4; ++nt)
            vbw_[chl * 72 + nt * 16 + l15] = f2b(va[1][mt][nt][r] * so.x + so.y);
        }
    }

    // v_local: lane = (half, cl); 8 positions per lane; row cached in rv[7]
    {
      const int cl   = lane & 31;
      const int half = lane >> 5;
      const int gch  = p * 256 + wave * 32 + cl;
      const __hip_bfloat16* vrow = vsm + wave * 2304 + cl * 72;
      bf16x8 rv[7];
      #pragma unroll
      for (int t = 0; t < 7; ++t) rv[t] = ld8(vrow + t * 8);
      float wv[9];
      #pragma unroll
      for (int j = 0; j < 9; ++j) wv[j] = vlw[gch * 9 + j];
      const float2 so = bnt[BN_VL + gch];
      #pragma unroll
      for (int pp = 0; pp < 8; ++pp) {
        const int pos = half * 8 + pp;
        const int oh = pos >> 2, ow = pos & 3;
        float a = 0.f;
        #pragma unroll
        for (int kh = 0; kh < 3; ++kh) {
          const int ih = 2 * oh - 1 + kh;
          if (ih < 0 || ih > 6) continue;
          #pragma unroll
          for (int kwi = 0; kwi < 3; ++kwi) {
            const int iw = 2 * ow - 1 + kwi;
            if (iw < 0 || iw > 6) continue;
            const int e = ih * 7 + iw;      // compile-time after unroll
            a += wv[kh * 3 + kwi] * (float)rv[e >> 3][e & 7];
          }
        }
        rout[pos * 520 + gch] = f2b(a * so.x + so.y);
      }
    }

    // PV (head h = 4p + w/2): 2 M-tiles over own 32 ch; rout = relu(xa + vloc)
    {
      const int h = p * 4 + (wave >> 1);
      const __hip_bfloat16* vbw_ = vsm + wave * 2304;
      #pragma unroll
      for (int mt = 0; mt < 2; ++mt) {
        f32x4 acc = fzero();
        #pragma unroll
        for (int ks = 0; ks < 2; ++ks) {
          const int k0 = ks * 32 + quad * 8;
          bf16x8 avv = ld8(&vbw_[(mt * 16 + l15) * 72 + k0]);                    // A[ch][nk]
          bf16x8 bvv = ld8(&attnS[h * 1024 + l15 * 64 + (k0 ^ ((l15 & 7) << 3))]); // B[nq][nk]
          acc = __builtin_amdgcn_mfma_f32_16x16x32_bf16(avv, bvv, acc, 0, 0, 0);
        }
        #pragma unroll
        for (int r = 0; r < 4; ++r) {
          const int gch = p * 256 + wave * 32 + mt * 16 + quad * 4 + r;
          const int ad = l15 * 520 + gch;
          const float val = acc[r] + b2f(rout[ad]);
          rout[ad] = f2b(fmaxf(val, 0.f));
        }
      }
    }
  }
  __syncthreads();   // bar5 — rout complete

  // ---- PF: proj GEMM — 24 M-tiles over 8 waves (3 each)
  {
    const int mt0 = wave * 3;
    f32x4 acc[3];
    #pragma unroll
    for (int t = 0; t < 3; ++t) acc[t] = fzero();
    for (int ks = 0; ks < 16; ++ks) {
      const int c0 = ks * 32 + quad * 8;
      bf16x8 bv = ld8(&rout[l15 * 520 + c0]);
      #pragma unroll
      for (int t = 0; t < 3; ++t) {
        bf16x8 av = ld8(&pwb[((mt0 + t) * 16 + l15) * DHC + c0]);
        acc[t] = __builtin_amdgcn_mfma_f32_16x16x32_bf16(av, bv, acc[t], 0, 0, 0);
      }
    }
    float* outb = out + (size_t)b * (OUTC * 16);
    #pragma unroll
    for (int t = 0; t < 3; ++t)
      #pragma unroll
      for (int r = 0; r < 4; ++r) {
        const int oc = (mt0 + t) * 16 + quad * 4 + r;
        const float2 so = bnt[BN_P + oc];
        outb[oc * 16 + l15] = acc[t][r] * so.x + so.y;
      }
  }
}

extern "C" void kernel_launch(void* const* d_in, const int* in_sizes, int n_in,
                              void* d_out, int out_size, void* d_ws, size_t ws_size,
                              hipStream_t stream) {
  const float* x    = (const float*)d_in[0];
  const float* qlw  = (const float*)d_in[1];
  const float* qlb  = (const float*)d_in[2];
  const float* qpw  = (const float*)d_in[3];
  const float* qpb  = (const float*)d_in[4];
  const float* qbn  = (const float*)d_in[5];
  const float* kw   = (const float*)d_in[6];
  const float* kb   = (const float*)d_in[7];
  const float* kbn  = (const float*)d_in[8];
  const float* vw   = (const float*)d_in[9];
  const float* vb   = (const float*)d_in[10];
  const float* vbn  = (const float*)d_in[11];
  const float* vlw  = (const float*)d_in[12];
  const float* vlb  = (const float*)d_in[13];
  const float* vlbn = (const float*)d_in[14];
  const float* pw   = (const float*)d_in[15];
  const float* pb   = (const float*)d_in[16];
  const float* pbn  = (const float*)d_in[17];
  const float* ab   = (const float*)d_in[18];
  const int*   bidx = (const int*)d_in[19];
  const int n_off = in_sizes[18] / 8;
  const int Bn = in_sizes[0] / (DIMC * NPOS);   // 2048

  __hip_bfloat16* wsb = (__hip_bfloat16*)d_ws;  // 983 KB weights + 13 KB BN + 25 KB abf

  prep_weights<<<480, 256, 0, stream>>>(kw, vw, qpw, pw,
                                        kb, kbn, qpb, qbn, vb, vbn,
                                        vlb, vlbn, pb, pbn, ab, bidx, n_off, wsb);
  attn4d_kernel<<<Bn, 512, 0, stream>>>(x, qlw, qlb, vlw, wsb, (float*)d_out);
}